// Round 5
// baseline (1533.555 us; speedup 1.0000x reference)
//
#include <hip/hip_runtime.h>
#include <hip/hip_bf16.h>
#include <stdint.h>

// D-MPNN (chemprop MPNEncoder) forward. fp32 in/out; bf16 intermediates, MFMA GEMMs.
// Intermediates use a 320-col padded layout (cols 300..319 == 0).
// Fused-K identity: relu(inp + m@W_h) = relu([m | f_bonds] @ [[W_h];[W_i]]), K=480.
// R5 changes vs R4 (latency-bound: random A-rows inside barriered K-loop):
//  - bond_diff kernel precomputes msgdiff = amsg[b2a]-msg[b2revb] into k-tiled
//    Abuf[tile][kt][128][64B] -> GEMM A-stage = contiguous 8KB streaming read
//  - GEMM tile 128x320 (rows/wave 2x -> B-traffic per FLOP halved)
//  - epilogue LDS staging padded (656B rows) to kill 8-way bank conflicts

#define H_DIM 300
#define HP 320
#define AF_DIM 133
#define BF_DIM 147
#define MAXNB 6

typedef __hip_bfloat16 bf16;
typedef __attribute__((ext_vector_type(8))) short short8;
typedef __attribute__((ext_vector_type(4))) float f32x4;

__device__ __forceinline__ float b2f_raw(unsigned short u) {
    union { unsigned int i; float f; } v; v.i = ((unsigned int)u) << 16; return v.f;
}
__device__ __forceinline__ unsigned short f2b_raw(float f) {
    union { float f; unsigned int i; } v; v.f = f;
    unsigned int x = v.i;
    x += 0x7fffu + ((x >> 16) & 1u);   // RNE
    return (unsigned short)(x >> 16);
}

// ---------------------------------------------------------------------------
// Weight prep: Wt[n][k] (bf16, k-contiguous, n<320, k<nkt*32)
//   k < 320 : s1[k*300 + n] (k < r1);  k >= 320: s2[(k-320)*300 + n] (k-320 < r2)
// ---------------------------------------------------------------------------
__global__ __launch_bounds__(256) void prep_wt(
    const float* __restrict__ s1, int r1,
    const float* __restrict__ s2, int r2,
    unsigned short* __restrict__ Wt, int nkt)
{
    const int Ktot = nkt * 32;
    const int idx = blockIdx.x * 256 + threadIdx.x;
    if (idx >= 320 * Ktot) return;
    const int n = idx % 320;
    const int k = idx / 320;
    float v = 0.f;
    if (n < H_DIM) {
        if (k < 320) { if (k < r1) v = s1[k * H_DIM + n]; }
        else { const int kk = k - 320; if (kk < r2) v = s2[kk * H_DIM + n]; }
    }
    Wt[n * Ktot + k] = f2b_raw(v);
}

// ---------------------------------------------------------------------------
// bond_diff: Abuf[T][kt][r][j*16B] = amsg[b2a[T*128+r]][kt*32+j*8 ..+8]
//                                  - msg[b2revb[...]][same]     (kt 0..9)
// 512 threads: r = t>>2, j = t&3. Reads 64B/row coalesced; writes 8KB contig.
// ---------------------------------------------------------------------------
__global__ __launch_bounds__(512) void bond_diff(
    const bf16* __restrict__ amsg, const bf16* __restrict__ msg,
    const int* __restrict__ b2a, const int* __restrict__ b2revb,
    bf16* __restrict__ Abuf, int n_bonds)
{
    const int T = blockIdx.x;
    const int t = threadIdx.x;
    const int r = t >> 2;
    const int j = t & 3;
    const int b = T * 128 + r;
    const bool ok = (b < n_bonds);
    long ra = 0, rb = 0;
    if (ok) { ra = b2a[b]; rb = b2revb[b]; }
    char* dst = (char*)Abuf + (long)T * 81920 + r * 64 + j * 16;
    const char* pa = (const char*)amsg + ra * 640 + j * 16;
    const char* pb = (const char*)msg  + rb * 640 + j * 16;
#pragma unroll 2
    for (int kt = 0; kt < 10; ++kt) {
        uint4 v = {0u, 0u, 0u, 0u};
        if (ok) {
            const uint4 x = *(const uint4*)(pa + kt * 64);
            const uint4 y = *(const uint4*)(pb + kt * 64);
            const unsigned short* xp = (const unsigned short*)&x;
            const unsigned short* yp = (const unsigned short*)&y;
            unsigned short* vp = (unsigned short*)&v;
#pragma unroll
            for (int e = 0; e < 8; ++e)
                vp[e] = f2b_raw(b2f_raw(xp[e]) - b2f_raw(yp[e]));
        }
        *(uint4*)(dst + kt * 8192) = v;
    }
}

// ---------------------------------------------------------------------------
// MFMA GEMM: out[M][320] = relu(A @ W (+bias)). 256 thr, tile 128(M) x 320(N),
// BK=32. Wave w: cols [80w,80w+80), all 128 rows. acc 8x5 f32x4.
// MODE 1: kt 0..4   <- f_bonds fp32 (k = kt*32..)              NKT=5
// MODE 2: kt 0..9   <- Abuf (k-tiled streaming, 8KB/kt)
//         kt 10..14 <- f_bonds fp32                            NKT=15
// MODE 3: kt 0..9   <- amsg plain (row-sequential streaming)
//         kt 10..14 <- f_atoms fp32 (width 133)                NKT=15
// A LDS: row r chunk c at r*64 + (c^(r&3))*16, double-buffered 2x8KB.
// ---------------------------------------------------------------------------
template <int MODE>
__global__ __launch_bounds__(256, 2) void mfma_gemm(
    const bf16* __restrict__ Aplain,  // M3: amsg
    const bf16* __restrict__ Atiled,  // M2: Abuf
    const float* __restrict__ Afp,    // M1/M2: f_bonds; M3: f_atoms
    const unsigned short* __restrict__ Wt,  // [320][NKT*32]
    const float* __restrict__ bias,   // M3: b_o
    bf16* __restrict__ out,           // [M][320]
    int M)
{
    constexpr int NKT  = (MODE == 1) ? 5 : 15;
    constexpr int KTOT = NKT * 32;
    constexpr int FPW  = (MODE == 3) ? AF_DIM : BF_DIM;

    __shared__ char As[2][8192];      // 128 rows x 64B, double-buffered
    __shared__ char Cs[16 * 656];     // epilogue staging, padded rows

    const int t    = threadIdx.x;
    const int m0   = blockIdx.x * 128;
    const int wave = t >> 6;
    const int lane = t & 63;
    const int l16  = lane & 15;
    const int quad = lane >> 4;

    // A-stage mapping: row r (0..127), half h (0..1) -> 32B
    const int r = t >> 1;
    const int h = t & 1;
    const int gm = m0 + r;
    const bool mok = (gm < M);
    const int woff0 = r * 64 + (((2 * h)     ^ (r & 3)) << 4);
    const int woff1 = r * 64 + (((2 * h + 1) ^ (r & 3)) << 4);

    auto stage_fp = [&](int k0, uint4* v) {
        unsigned short* rp = (unsigned short*)v;
#pragma unroll
        for (int i = 0; i < 16; ++i) {
            const int kk = k0 + i;
            float f = 0.f;
            if (mok && kk < FPW) f = Afp[(long)gm * FPW + kk];
            rp[i] = f2b_raw(f);
        }
    };

    auto stage = [&](int kt, uint4* v) {
        if (MODE == 1) {
            stage_fp(kt * 32 + h * 16, v);
        } else if (kt < 10) {
            if (MODE == 2) {
                const char* src = (const char*)Atiled +
                    ((long)blockIdx.x * 10 + kt) * 8192 + t * 32;
                v[0] = *(const uint4*)src;
                v[1] = *(const uint4*)(src + 16);
            } else {
                if (mok) {
                    const char* src = (const char*)Aplain + (long)gm * 640 + kt * 64 + h * 32;
                    v[0] = *(const uint4*)src;
                    v[1] = *(const uint4*)(src + 16);
                } else {
                    v[0] = (uint4){0u,0u,0u,0u}; v[1] = (uint4){0u,0u,0u,0u};
                }
            }
        } else {
            stage_fp((kt - 10) * 32 + h * 16, v);
        }
    };

    auto load_b = [&](int kt, short8* bfr) {
        const int kbase = kt * 32 + quad * 8;
#pragma unroll
        for (int nt = 0; nt < 5; ++nt) {
            const int nn = wave * 80 + nt * 16 + l16;
            bfr[nt] = *(const short8*)(Wt + (long)nn * KTOT + kbase);
        }
    };

    f32x4 acc[8][5];
#pragma unroll
    for (int i = 0; i < 8; ++i)
#pragma unroll
        for (int j = 0; j < 5; ++j) acc[i][j] = (f32x4){0.f, 0.f, 0.f, 0.f};

    // prologue
    uint4 aval[2];
    stage(0, aval);
    *(uint4*)(As[0] + woff0) = aval[0];
    *(uint4*)(As[0] + woff1) = aval[1];
    short8 bfr[5];
    load_b(0, bfr);

    const int rdoff = l16 * 64 + ((quad ^ (l16 & 3)) << 4);

    for (int kt = 0; kt < NKT; ++kt) {
        uint4 anext[2];
        short8 bfr_n[5];
        if (kt + 1 < NKT) {
            stage(kt + 1, anext);
            load_b(kt + 1, bfr_n);
        }
        __syncthreads();
        const char* Ac = As[kt & 1];
#pragma unroll
        for (int g = 0; g < 2; ++g) {
            short8 afr[4];
#pragma unroll
            for (int i = 0; i < 4; ++i)
                afr[i] = *(const short8*)(Ac + (g * 4 + i) * 1024 + rdoff);
#pragma unroll
            for (int nt = 0; nt < 5; ++nt)
#pragma unroll
                for (int i = 0; i < 4; ++i)
                    acc[g * 4 + i][nt] = __builtin_amdgcn_mfma_f32_16x16x32_bf16(
                        afr[i], bfr[nt], acc[g * 4 + i][nt], 0, 0, 0);
        }
        if (kt + 1 < NKT) {
            *(uint4*)(As[(kt + 1) & 1] + woff0) = anext[0];
            *(uint4*)(As[(kt + 1) & 1] + woff1) = anext[1];
#pragma unroll
            for (int nt = 0; nt < 5; ++nt) bfr[nt] = bfr_n[nt];
        }
    }

    // epilogue: 8 strips of 16 rows via padded LDS -> coalesced 16B stores
    for (int s = 0; s < 8; ++s) {
        __syncthreads();
#pragma unroll
        for (int nt = 0; nt < 5; ++nt) {
            const int col = wave * 80 + nt * 16 + l16;
            float bv = 0.f;
            if (MODE == 3) bv = (col < H_DIM) ? bias[col] : 0.f;
#pragma unroll
            for (int rr = 0; rr < 4; ++rr) {
                const float v = fmaxf(acc[s][nt][rr] + bv, 0.f);
                *(unsigned short*)(Cs + (quad * 4 + rr) * 656 + col * 2) = f2b_raw(v);
            }
        }
        __syncthreads();
        const int gr0 = m0 + s * 16;
#pragma unroll
        for (int i = 0; i < 3; ++i) {
            const int idx = i * 256 + t;
            if (idx < 640) {
                const int row = idx / 40;
                const int j   = idx - row * 40;
                if (gr0 + row < M)
                    *(uint4*)((char*)out + (long)(gr0 + row) * 640 + j * 16)
                        = *(const uint4*)(Cs + row * 656 + j * 16);
            }
        }
    }
}

// amsg[a][0:320] = sum_{j<6} msg[a2b[a][j]][0:320]; thread = (atom, 16B chunk)
__global__ __launch_bounds__(256) void gather_sum_kernel(
    const bf16* __restrict__ msg, const int* __restrict__ a2b,
    bf16* __restrict__ amsg, int n_atoms)
{
    const int idx = blockIdx.x * 256 + threadIdx.x;
    if (idx >= n_atoms * (HP / 8)) return;
    const int a = idx / (HP / 8);
    const int cc = idx - a * (HP / 8);
    float s[8] = {0.f, 0.f, 0.f, 0.f, 0.f, 0.f, 0.f, 0.f};
    const int base = a * MAXNB;
#pragma unroll
    for (int j = 0; j < MAXNB; ++j) {
        const long b = a2b[base + j];
        const uint4 u = *(const uint4*)((const char*)msg + (b * HP + cc * 8) * 2);
        const unsigned short* up = (const unsigned short*)&u;
#pragma unroll
        for (int e = 0; e < 8; ++e) s[e] += b2f_raw(up[e]);
    }
    uint4 rv;
    unsigned short* rp = (unsigned short*)&rv;
#pragma unroll
    for (int e = 0; e < 8; ++e) rp[e] = f2b_raw(s[e]);
    *(uint4*)((char*)amsg + ((long)a * HP + cc * 8) * 2) = rv;
}

// Per-molecule mean; atom_mol sorted ascending -> binary search, no atomics.
__global__ __launch_bounds__(256) void seg_mean_kernel(
    const bf16* __restrict__ hidden, const int* __restrict__ atom_mol,
    float* __restrict__ out, int n_atoms)
{
    const int m = blockIdx.x;
    __shared__ int s_lo, s_hi;
    if (threadIdx.x == 0) {
        int lo = 0, hi = n_atoms;
        while (lo < hi) { int mid = (lo + hi) >> 1; if (atom_mol[mid] < m) lo = mid + 1; else hi = mid; }
        s_lo = lo;
        int lo2 = lo; hi = n_atoms;
        while (lo2 < hi) { int mid = (lo2 + hi) >> 1; if (atom_mol[mid] < m + 1) lo2 = mid + 1; else hi = mid; }
        s_hi = lo2;
    }
    __syncthreads();
    const int lo = s_lo, hi = s_hi;
    const float inv = 1.0f / (float)max(hi - lo, 1);
    for (int cpass = 0; cpass < 2; ++cpass) {
        const int c = cpass * 256 + threadIdx.x;
        if (c >= H_DIM) break;
        float s = 0.f;
        for (int a = lo; a < hi; ++a)
            s += b2f_raw(((const unsigned short*)hidden)[(long)a * HP + c]);
        out[(long)m * H_DIM + c] = s * inv;
    }
}

extern "C" void kernel_launch(void* const* d_in, const int* in_sizes, int n_in,
                              void* d_out, int out_size, void* d_ws, size_t ws_size,
                              hipStream_t stream)
{
    const float* f_atoms = (const float*)d_in[0];
    const float* f_bonds = (const float*)d_in[1];
    const float* W_i     = (const float*)d_in[2];
    const float* W_h     = (const float*)d_in[3];
    const float* W_o     = (const float*)d_in[4];
    const float* b_o     = (const float*)d_in[5];
    const int*  a2b      = (const int*)d_in[6];
    const int*  b2a      = (const int*)d_in[7];
    const int*  b2revb   = (const int*)d_in[8];
    const int*  atom_mol = (const int*)d_in[9];

    const int n_atoms = in_sizes[0] / AF_DIM;   // 100000
    const int n_bonds = in_sizes[1] / BF_DIM;   // 200000
    const int n_mols  = out_size / H_DIM;       // 4000

    const int TB = (n_bonds + 127) / 128;       // 1563 bond tiles
    const int TA = (n_atoms + 127) / 128;       // 782 atom tiles

    char* ws = (char*)d_ws;
    size_t off = 0;
    auto alloc = [&](size_t bytes) {
        size_t o = off; off += (bytes + 255) & ~(size_t)255; return o;
    };
    bf16* msgA = (bf16*)(ws + alloc((size_t)n_bonds * HP * 2));   // 128 MB
    bf16* msgB = (bf16*)(ws + alloc((size_t)n_bonds * HP * 2));   // 128 MB
    bf16* amsg = (bf16*)(ws + alloc((size_t)n_atoms * HP * 2));   //  64 MB
    bf16* Abuf = (bf16*)(ws + alloc((size_t)TB * 81920));         // 128 MB k-tiled
    unsigned short* Wt1 = (unsigned short*)(ws + alloc(320 * 160 * 2));
    unsigned short* Wt2 = (unsigned short*)(ws + alloc(320 * 480 * 2));
    unsigned short* Wt3 = (unsigned short*)(ws + alloc(320 * 480 * 2));
    bf16* hidden = msgB;  // msgB dead by GEMM3

    const dim3 blk(256);

    prep_wt<<<(320 * 160 + 255) / 256, blk, 0, stream>>>(W_i, BF_DIM, nullptr, 0, Wt1, 5);
    prep_wt<<<(320 * 480 + 255) / 256, blk, 0, stream>>>(W_h, H_DIM, W_i, BF_DIM, Wt2, 15);
    prep_wt<<<(320 * 480 + 255) / 256, blk, 0, stream>>>(W_o + (size_t)AF_DIM * H_DIM, H_DIM,
                                                         W_o, AF_DIM, Wt3, 15);

    const int gG = (n_atoms * (HP / 8) + 255) / 256;

    // msg0 = relu(f_bonds @ W_i)
    mfma_gemm<1><<<TB, blk, 0, stream>>>(nullptr, nullptr, f_bonds, Wt1, nullptr, msgA, n_bonds);
    // depth 1: msgA -> msgB
    gather_sum_kernel<<<gG, blk, 0, stream>>>(msgA, a2b, amsg, n_atoms);
    bond_diff<<<TB, dim3(512), 0, stream>>>(amsg, msgA, b2a, b2revb, Abuf, n_bonds);
    mfma_gemm<2><<<TB, blk, 0, stream>>>(nullptr, Abuf, f_bonds, Wt2, nullptr, msgB, n_bonds);
    // depth 2: msgB -> msgA
    gather_sum_kernel<<<gG, blk, 0, stream>>>(msgB, a2b, amsg, n_atoms);
    bond_diff<<<TB, dim3(512), 0, stream>>>(amsg, msgB, b2a, b2revb, Abuf, n_bonds);
    mfma_gemm<2><<<TB, blk, 0, stream>>>(nullptr, Abuf, f_bonds, Wt2, nullptr, msgA, n_bonds);
    // final aggregation + readout
    gather_sum_kernel<<<gG, blk, 0, stream>>>(msgA, a2b, amsg, n_atoms);
    mfma_gemm<3><<<TA, blk, 0, stream>>>(amsg, nullptr, f_atoms, Wt3, b_o, hidden, n_atoms);
    // per-molecule mean
    seg_mean_kernel<<<n_mols, blk, 0, stream>>>(hidden, atom_mol, (float*)d_out, n_atoms);
}

// Round 6
// 1075.810 us; speedup vs baseline: 1.4255x; 1.4255x over previous
//
#include <hip/hip_runtime.h>
#include <hip/hip_bf16.h>
#include <stdint.h>

// D-MPNN (chemprop MPNEncoder) forward. fp32 in/out; bf16 intermediates, MFMA GEMMs.
// Intermediates use a 320-col padded layout (cols 300..319 == 0).
// Fused-K identity: relu(inp + m@W_h) = relu([m | f_bonds] @ [[W_h];[W_i]]), K=480.
// R6 = R4's proven 64x320 GEMM shape (acc 4x5 = 80 VGPRs/lane -- R5's 128x320
// tile needed 160 and spilled: 2GB scratch writes, MfmaUtil 2.5%) + R5's
// bond_diff streaming-A idea (random gather rows moved OUT of the barriered
// K-loop into a pure-BW kernel writing k-tiled Abuf).

#define H_DIM 300
#define HP 320
#define AF_DIM 133
#define BF_DIM 147
#define MAXNB 6

typedef __hip_bfloat16 bf16;
typedef __attribute__((ext_vector_type(8))) short short8;
typedef __attribute__((ext_vector_type(4))) float f32x4;

__device__ __forceinline__ float b2f_raw(unsigned short u) {
    union { unsigned int i; float f; } v; v.i = ((unsigned int)u) << 16; return v.f;
}
__device__ __forceinline__ unsigned short f2b_raw(float f) {
    union { float f; unsigned int i; } v; v.f = f;
    unsigned int x = v.i;
    x += 0x7fffu + ((x >> 16) & 1u);   // RNE
    return (unsigned short)(x >> 16);
}

// ---------------------------------------------------------------------------
// Weight prep: Wt[n][k] (bf16, k-contiguous, n<320, k<nkt*32)
//   k < 320 : s1[k*300 + n] (k < r1);  k >= 320: s2[(k-320)*300 + n] (k-320 < r2)
// ---------------------------------------------------------------------------
__global__ __launch_bounds__(256) void prep_wt(
    const float* __restrict__ s1, int r1,
    const float* __restrict__ s2, int r2,
    unsigned short* __restrict__ Wt, int nkt)
{
    const int Ktot = nkt * 32;
    const int idx = blockIdx.x * 256 + threadIdx.x;
    if (idx >= 320 * Ktot) return;
    const int n = idx % 320;
    const int k = idx / 320;
    float v = 0.f;
    if (n < H_DIM) {
        if (k < 320) { if (k < r1) v = s1[k * H_DIM + n]; }
        else { const int kk = k - 320; if (kk < r2) v = s2[kk * H_DIM + n]; }
    }
    Wt[n * Ktot + k] = f2b_raw(v);
}

// ---------------------------------------------------------------------------
// bond_diff: Abuf[T][kt][r][j] = amsg[b2a[T*64+r]][kt*32+j*8..+8]
//                              - msg[b2revb[...]][same]   (kt 0..9, 16B chunks)
// 256 threads: r = t>>2 (0..63), j = t&3. Coalesced 64B row reads; 4KB contig writes.
// ---------------------------------------------------------------------------
__global__ __launch_bounds__(256) void bond_diff(
    const bf16* __restrict__ amsg, const bf16* __restrict__ msg,
    const int* __restrict__ b2a, const int* __restrict__ b2revb,
    bf16* __restrict__ Abuf, int n_bonds)
{
    const int T = blockIdx.x;
    const int t = threadIdx.x;
    const int r = t >> 2;
    const int j = t & 3;
    const int b = T * 64 + r;
    const bool ok = (b < n_bonds);
    long ra = 0, rb = 0;
    if (ok) { ra = b2a[b]; rb = b2revb[b]; }
    char* dst = (char*)Abuf + (long)T * 40960 + t * 16;
    const char* pa = (const char*)amsg + ra * 640 + j * 16;
    const char* pb = (const char*)msg  + rb * 640 + j * 16;
#pragma unroll 2
    for (int kt = 0; kt < 10; ++kt) {
        uint4 v = {0u, 0u, 0u, 0u};
        if (ok) {
            const uint4 x = *(const uint4*)(pa + kt * 64);
            const uint4 y = *(const uint4*)(pb + kt * 64);
            const unsigned short* xp = (const unsigned short*)&x;
            const unsigned short* yp = (const unsigned short*)&y;
            unsigned short* vp = (unsigned short*)&v;
#pragma unroll
            for (int e = 0; e < 8; ++e)
                vp[e] = f2b_raw(b2f_raw(xp[e]) - b2f_raw(yp[e]));
        }
        *(uint4*)(dst + kt * 4096) = v;
    }
}

// ---------------------------------------------------------------------------
// MFMA GEMM: out[M][320] = relu(A @ W (+bias)). 256 thr, tile 64(M) x 320(N),
// BK=32. Wave w: cols [80w, 80w+80). acc 4x5 f32x4 (80 VGPRs).
// MODE 1: kt 0..4   <- f_bonds fp32;                         NKT=5
// MODE 2: kt 0..9   <- Abuf (k-tiled, contiguous 4KB per kt)
//         kt 10..14 <- f_bonds fp32;                         NKT=15
// MODE 3: kt 0..9   <- amsg (row-sequential); kt 10..14 <- f_atoms; NKT=15
// A LDS: row r chunk c at r*64 + ((c^(r&3))<<4), double-buffered 2x4KB.
// ---------------------------------------------------------------------------
template <int MODE>
__global__ __launch_bounds__(256, 2) void mfma_gemm(
    const bf16* __restrict__ Ab,    // M3: amsg
    const bf16* __restrict__ Atiled,// M2: Abuf
    const float* __restrict__ Afp,  // M1/M2: f_bonds; M3: f_atoms
    const unsigned short* __restrict__ Wt,  // [320][NKT*32]
    const float* __restrict__ bias, // M3: b_o
    bf16* __restrict__ out,         // [M][320]
    int M)
{
    constexpr int NKT  = (MODE == 1) ? 5 : 15;
    constexpr int KTOT = NKT * 32;
    constexpr int FPW  = (MODE == 3) ? AF_DIM : BF_DIM;

    __shared__ char As[2][64 * 64];   // 2 x 4KB double-buffered A
    __shared__ char Cs[16 * 656];     // epilogue staging, padded rows

    const int t    = threadIdx.x;
    const int m0   = blockIdx.x * 64;
    const int wave = t >> 6;
    const int lane = t & 63;
    const int l16  = lane & 15;
    const int quad = lane >> 4;

    // A-staging mapping: row am (0..63), chunk c (0..3)
    const int am  = t >> 2;
    const int c   = t & 3;
    const int gm  = m0 + am;
    const bool mok = (gm < M);
    const int aoff = am * 64 + ((c ^ (am & 3)) << 4);

    auto load_a = [&](int kt) -> uint4 {
        uint4 aval = {0u, 0u, 0u, 0u};
        if (MODE == 2 && kt < 10) {
            // contiguous k-tiled stream (no bounds check needed: Abuf padded)
            return *(const uint4*)((const char*)Atiled +
                                   ((long)blockIdx.x * 10 + kt) * 4096 + t * 16);
        }
        if (!mok) return aval;
        if (MODE == 3 && kt < 10) {
            const int k = kt * 32 + c * 8;
            return *(const uint4*)((const char*)Ab + ((long)gm * HP + k) * 2);
        }
        // fp32 part (MODE 1: kt 0..4 k=kt*32; MODE 2/3 tail: k=(kt-10)*32)
        const int k0 = (MODE == 1 ? kt : kt - 10) * 32 + c * 8;
        unsigned short* rp = (unsigned short*)&aval;
#pragma unroll
        for (int jj = 0; jj < 8; ++jj) {
            const int kk = k0 + jj;
            rp[jj] = (kk < FPW) ? f2b_raw(Afp[(long)gm * FPW + kk]) : 0;
        }
        return aval;
    };

    auto load_b = [&](int kt, short8* bfr) {
        const int kbase = kt * 32 + quad * 8;
#pragma unroll
        for (int nt = 0; nt < 5; ++nt) {
            const int nn = wave * 80 + nt * 16 + l16;
            bfr[nt] = *(const short8*)(Wt + (long)nn * KTOT + kbase);
        }
    };

    f32x4 acc[4][5];
#pragma unroll
    for (int i = 0; i < 4; ++i)
#pragma unroll
        for (int j = 0; j < 5; ++j) acc[i][j] = (f32x4){0.f, 0.f, 0.f, 0.f};

    // prologue: stage A(0), fetch B(0)
    uint4 aval = load_a(0);
    *(uint4*)(As[0] + aoff) = aval;
    short8 bfr[5];
    load_b(0, bfr);

    const int rdoff = l16 * 64 + ((quad ^ (l16 & 3)) << 4);

    for (int kt = 0; kt < NKT; ++kt) {
        uint4 anext;
        short8 bfr_n[5];
        if (kt + 1 < NKT) {                 // prefetch next iteration (global)
            anext = load_a(kt + 1);
            load_b(kt + 1, bfr_n);
        }
        __syncthreads();                    // As[kt&1] visible to all waves
        short8 afr[4];
#pragma unroll
        for (int mt = 0; mt < 4; ++mt)
            afr[mt] = *(const short8*)(As[kt & 1] + mt * 1024 + rdoff);
#pragma unroll
        for (int nt = 0; nt < 5; ++nt)
#pragma unroll
            for (int mt = 0; mt < 4; ++mt)
                acc[mt][nt] = __builtin_amdgcn_mfma_f32_16x16x32_bf16(
                    afr[mt], bfr[nt], acc[mt][nt], 0, 0, 0);
        if (kt + 1 < NKT) {
            *(uint4*)(As[(kt + 1) & 1] + aoff) = anext;  // buffer last read in kt-1
#pragma unroll
            for (int nt = 0; nt < 5; ++nt) bfr[nt] = bfr_n[nt];
        }
    }

    // epilogue: per 16-row strip, padded LDS staging -> coalesced 16B stores
    for (int mt = 0; mt < 4; ++mt) {
        __syncthreads();
#pragma unroll
        for (int nt = 0; nt < 5; ++nt) {
            const int col = wave * 80 + nt * 16 + l16;
            float bv = 0.f;
            if (MODE == 3) bv = (col < H_DIM) ? bias[col] : 0.f;
#pragma unroll
            for (int r = 0; r < 4; ++r) {
                const float v = fmaxf(acc[mt][nt][r] + bv, 0.f);
                *(unsigned short*)(Cs + (quad * 4 + r) * 656 + col * 2) = f2b_raw(v);
            }
        }
        __syncthreads();
        const int gr0 = m0 + mt * 16;
#pragma unroll
        for (int i = 0; i < 3; ++i) {       // 640 16B-chunks, 256 threads
            const int idx = i * 256 + t;
            if (idx < 640) {
                const int row = idx / 40;   // 40 chunks per 640B row
                const int j   = idx - row * 40;
                if (gr0 + row < M)
                    *(uint4*)((char*)out + (long)(gr0 + row) * 640 + j * 16)
                        = *(const uint4*)(Cs + row * 656 + j * 16);
            }
        }
    }
}

// amsg[a][0:320] = sum_{j<6} msg[a2b[a][j]][0:320]; thread = (atom, 16B chunk)
__global__ __launch_bounds__(256) void gather_sum_kernel(
    const bf16* __restrict__ msg, const int* __restrict__ a2b,
    bf16* __restrict__ amsg, int n_atoms)
{
    const int idx = blockIdx.x * 256 + threadIdx.x;
    if (idx >= n_atoms * (HP / 8)) return;
    const int a = idx / (HP / 8);
    const int cc = idx - a * (HP / 8);
    float s[8] = {0.f, 0.f, 0.f, 0.f, 0.f, 0.f, 0.f, 0.f};
    const int base = a * MAXNB;
#pragma unroll
    for (int j = 0; j < MAXNB; ++j) {
        const long b = a2b[base + j];
        const uint4 u = *(const uint4*)((const char*)msg + (b * HP + cc * 8) * 2);
        const unsigned short* up = (const unsigned short*)&u;
#pragma unroll
        for (int e = 0; e < 8; ++e) s[e] += b2f_raw(up[e]);
    }
    uint4 rv;
    unsigned short* rp = (unsigned short*)&rv;
#pragma unroll
    for (int e = 0; e < 8; ++e) rp[e] = f2b_raw(s[e]);
    *(uint4*)((char*)amsg + ((long)a * HP + cc * 8) * 2) = rv;
}

// Per-molecule mean; atom_mol sorted ascending -> binary search, no atomics.
__global__ __launch_bounds__(256) void seg_mean_kernel(
    const bf16* __restrict__ hidden, const int* __restrict__ atom_mol,
    float* __restrict__ out, int n_atoms)
{
    const int m = blockIdx.x;
    __shared__ int s_lo, s_hi;
    if (threadIdx.x == 0) {
        int lo = 0, hi = n_atoms;
        while (lo < hi) { int mid = (lo + hi) >> 1; if (atom_mol[mid] < m) lo = mid + 1; else hi = mid; }
        s_lo = lo;
        int lo2 = lo; hi = n_atoms;
        while (lo2 < hi) { int mid = (lo2 + hi) >> 1; if (atom_mol[mid] < m + 1) lo2 = mid + 1; else hi = mid; }
        s_hi = lo2;
    }
    __syncthreads();
    const int lo = s_lo, hi = s_hi;
    const float inv = 1.0f / (float)max(hi - lo, 1);
    for (int cpass = 0; cpass < 2; ++cpass) {
        const int c = cpass * 256 + threadIdx.x;
        if (c >= H_DIM) break;
        float s = 0.f;
        for (int a = lo; a < hi; ++a)
            s += b2f_raw(((const unsigned short*)hidden)[(long)a * HP + c]);
        out[(long)m * H_DIM + c] = s * inv;
    }
}

extern "C" void kernel_launch(void* const* d_in, const int* in_sizes, int n_in,
                              void* d_out, int out_size, void* d_ws, size_t ws_size,
                              hipStream_t stream)
{
    const float* f_atoms = (const float*)d_in[0];
    const float* f_bonds = (const float*)d_in[1];
    const float* W_i     = (const float*)d_in[2];
    const float* W_h     = (const float*)d_in[3];
    const float* W_o     = (const float*)d_in[4];
    const float* b_o     = (const float*)d_in[5];
    const int*  a2b      = (const int*)d_in[6];
    const int*  b2a      = (const int*)d_in[7];
    const int*  b2revb   = (const int*)d_in[8];
    const int*  atom_mol = (const int*)d_in[9];

    const int n_atoms = in_sizes[0] / AF_DIM;   // 100000
    const int n_bonds = in_sizes[1] / BF_DIM;   // 200000
    const int n_mols  = out_size / H_DIM;       // 4000

    const int TB = (n_bonds + 63) / 64;         // 3125 bond tiles
    const int TA = (n_atoms + 63) / 64;         // 1563 atom tiles

    char* ws = (char*)d_ws;
    size_t off = 0;
    auto alloc = [&](size_t bytes) {
        size_t o = off; off += (bytes + 255) & ~(size_t)255; return o;
    };
    bf16* msgA = (bf16*)(ws + alloc((size_t)n_bonds * HP * 2));   // 128 MB
    bf16* msgB = (bf16*)(ws + alloc((size_t)n_bonds * HP * 2));   // 128 MB
    bf16* amsg = (bf16*)(ws + alloc((size_t)n_atoms * HP * 2));   //  64 MB
    bf16* Abuf = (bf16*)(ws + alloc((size_t)TB * 40960));         // 128 MB k-tiled
    unsigned short* Wt1 = (unsigned short*)(ws + alloc(320 * 160 * 2));
    unsigned short* Wt2 = (unsigned short*)(ws + alloc(320 * 480 * 2));
    unsigned short* Wt3 = (unsigned short*)(ws + alloc(320 * 480 * 2));
    bf16* hidden = msgB;  // msgB dead by GEMM3

    const dim3 blk(256);

    prep_wt<<<(320 * 160 + 255) / 256, blk, 0, stream>>>(W_i, BF_DIM, nullptr, 0, Wt1, 5);
    prep_wt<<<(320 * 480 + 255) / 256, blk, 0, stream>>>(W_h, H_DIM, W_i, BF_DIM, Wt2, 15);
    prep_wt<<<(320 * 480 + 255) / 256, blk, 0, stream>>>(W_o + (size_t)AF_DIM * H_DIM, H_DIM,
                                                         W_o, AF_DIM, Wt3, 15);

    const int gG = (n_atoms * (HP / 8) + 255) / 256;

    // msg0 = relu(f_bonds @ W_i)
    mfma_gemm<1><<<TB, blk, 0, stream>>>(nullptr, nullptr, f_bonds, Wt1, nullptr, msgA, n_bonds);
    // depth 1: msgA -> msgB
    gather_sum_kernel<<<gG, blk, 0, stream>>>(msgA, a2b, amsg, n_atoms);
    bond_diff<<<TB, blk, 0, stream>>>(amsg, msgA, b2a, b2revb, Abuf, n_bonds);
    mfma_gemm<2><<<TB, blk, 0, stream>>>(nullptr, Abuf, f_bonds, Wt2, nullptr, msgB, n_bonds);
    // depth 2: msgB -> msgA
    gather_sum_kernel<<<gG, blk, 0, stream>>>(msgB, a2b, amsg, n_atoms);
    bond_diff<<<TB, blk, 0, stream>>>(amsg, msgB, b2a, b2revb, Abuf, n_bonds);
    mfma_gemm<2><<<TB, blk, 0, stream>>>(nullptr, Abuf, f_bonds, Wt2, nullptr, msgA, n_bonds);
    // final aggregation + readout
    gather_sum_kernel<<<gG, blk, 0, stream>>>(msgA, a2b, amsg, n_atoms);
    mfma_gemm<3><<<TA, blk, 0, stream>>>(amsg, nullptr, f_atoms, Wt3, b_o, hidden, n_atoms);
    // per-molecule mean
    seg_mean_kernel<<<n_mols, blk, 0, stream>>>(hidden, atom_mol, (float*)d_out, n_atoms);
}